// Round 20
// baseline (422.312 us; speedup 1.0000x reference)
//
#include <hip/hip_runtime.h>
#include <hip/hip_fp16.h>
#include <stdint.h>

// ---------------------------------------------------------------------------
// GIN (4 layers, CSR gather aggregation) + MLP classifier, bf16 MFMA GEMMs.
// R20 change: cls_kernel __launch_bounds__(1024, 4).
//   R19's 16-wave cls spilled (WRITE 0.39->30.7MB scratch, VGPR capped at 64:
//   compiler budgeted for an occupancy the 144KB-LDS kernel can't reach).
//   At 1 block/CU = 4 waves/SIMD the budget is 512/4 = 128 VGPR; declaring
//   min-waves/EU=4 lifts the cap -> ~80-reg live set fits, no spill. This is
//   the clean test of 4 waves/SIMD that R19 failed to run.
//   Everything else identical to R18/R19 (fp8 agg ~64us floor, GEMM v5).
// ---------------------------------------------------------------------------

#define NN  100000
#define EE  1600000
#define CIN 64
#define CC  128
#define NBK 782              // ceil(NN / 128) buckets, bucket = dst >> 7
#define CHUNK 8192           // edges per multi-split block
#define NCH 196              // ceil(EE / CHUNK)

typedef __attribute__((ext_vector_type(8))) __bf16 bf16x8;
typedef __attribute__((ext_vector_type(4))) float  f32x4;
typedef __attribute__((ext_vector_type(2))) float  f32x2;

__device__ __forceinline__ float bf2f(uint32_t u) { return __uint_as_float(u << 16); }
__device__ __forceinline__ float bf2f_hi(uint32_t u) { return __uint_as_float(u & 0xffff0000u); }
__device__ __forceinline__ ushort f2bf(float f) {          // RNE f32 -> bf16
  uint32_t u = __float_as_uint(f);
  u += 0x7fffu + ((u >> 16) & 1u);
  return (ushort)(u >> 16);
}

#if __has_builtin(__builtin_amdgcn_cvt_pk_f32_bf8) && __has_builtin(__builtin_amdgcn_cvt_pk_bf8_f32)
#define F8_HW 1
#endif

// decode 2 e5m2 bytes (word HI of dword d) -> 2 f32
template<bool HI> __device__ __forceinline__ f32x2 dec_pk(uint d) {
#ifdef F8_HW
  return __builtin_amdgcn_cvt_pk_f32_bf8((int)d, HI);
#else
  uint w = HI ? (d >> 16) : d;
  f32x2 r;
  uint b0 = w & 0xFFu, b1 = (w >> 8) & 0xFFu;
  r.x = __uint_as_float(((b0 & 0x80u) << 24) | ((b0 & 0x7Fu) << 21)) * 0x1.0p112f;
  r.y = __uint_as_float(((b1 & 0x80u) << 24) | ((b1 & 0x7Fu) << 21)) * 0x1.0p112f;
  return r;
#endif
}
// encode 2 f32 -> 2 e5m2 bytes into word HI of old
template<bool HI> __device__ __forceinline__ uint enc_pk(float a, float b, uint old) {
#ifdef F8_HW
  return (uint)__builtin_amdgcn_cvt_pk_bf8_f32(a, b, (int)old, HI);
#else
  ushort ha = __half_as_ushort(__float2half(a));
  ushort hb = __half_as_ushort(__float2half(b));
  ha = (ushort)(ha + 0x7F + ((ha >> 8) & 1));
  hb = (ushort)(hb + 0x7F + ((hb >> 8) & 1));
  uint two = (uint)(ha >> 8) | ((uint)(hb >> 8) << 8);
  return HI ? ((old & 0x0000FFFFu) | (two << 16)) : ((old & 0xFFFF0000u) | two);
#endif
}

template<int ACT> __device__ __forceinline__ float actf(float z) {
  if constexpr (ACT == 1) return z >= 0.f ? z : 0.01f * z;       // lrelu
  else if constexpr (ACT == 2) return z >= 0.f ? z : 1e-4f * z;  // lrelu(lrelu)
  else return z;
}

// async global->LDS, 16B per lane; lds base must be wave-uniform
__device__ __forceinline__ void gload_lds16(const void* g, void* l) {
  __builtin_amdgcn_global_load_lds(
      (const __attribute__((address_space(1))) void*)g,
      (__attribute__((address_space(3))) void*)l, 16, 0, 0);
}

// ---------------- multi-split CSR build ----------------
__global__ __launch_bounds__(256) void ms_hist_kernel(const int* __restrict__ ei,
                                                      int* __restrict__ hist,
                                                      int* __restrict__ bh, int e) {
  __shared__ int h[NBK];
  for (int i = threadIdx.x; i < NBK; i += 256) h[i] = 0;
  __syncthreads();
  const int base = blockIdx.x * CHUNK;
  const int end = min(base + CHUNK, e);
  for (int i = base + threadIdx.x; i < end; i += 256)
    atomicAdd(&h[ei[e + i] >> 7], 1);
  __syncthreads();
  for (int i = threadIdx.x; i < NBK; i += 256) {
    hist[blockIdx.x * NBK + i] = h[i];
    if (h[i]) atomicAdd(&bh[i], h[i]);
  }
}

__global__ __launch_bounds__(256) void bkt_scan_kernel(const int* __restrict__ bh,
                                                       int* __restrict__ boff, int e) {
  __shared__ int sd[256];
  int t = threadIdx.x;
  int base = t * 4;
  int v0 = base + 0 < NBK ? bh[base + 0] : 0;
  int v1 = base + 1 < NBK ? bh[base + 1] : 0;
  int v2 = base + 2 < NBK ? bh[base + 2] : 0;
  int v3 = base + 3 < NBK ? bh[base + 3] : 0;
  int ts = v0 + v1 + v2 + v3;
  sd[t] = ts; __syncthreads();
  for (int off = 1; off < 256; off <<= 1) {
    int u = (t >= off) ? sd[t - off] : 0;
    __syncthreads();
    sd[t] += u;
    __syncthreads();
  }
  int excl = sd[t] - ts;
  if (base + 0 < NBK) boff[base + 0] = excl;
  if (base + 1 < NBK) boff[base + 1] = excl + v0;
  if (base + 2 < NBK) boff[base + 2] = excl + v0 + v1;
  if (base + 3 < NBK) boff[base + 3] = excl + v0 + v1 + v2;
  if (t == 255) boff[NBK] = e;
}

__global__ void ms_offs_kernel(int* __restrict__ hist, const int* __restrict__ boff) {
  int b = blockIdx.x * 256 + threadIdx.x;
  if (b >= NBK) return;
  int run = boff[b];
  for (int k = 0; k < NCH; ++k) {
    int t = hist[k * NBK + b];     // coalesced across b
    hist[k * NBK + b] = run;
    run += t;
  }
}

__global__ __launch_bounds__(256) void ms_scatter_kernel(const int* __restrict__ ei,
                                                         const int* __restrict__ hist,
                                                         uint* __restrict__ ebkt, int e) {
  __shared__ int cur[NBK];
  for (int i = threadIdx.x; i < NBK; i += 256) cur[i] = hist[blockIdx.x * NBK + i];
  __syncthreads();
  const int base = blockIdx.x * CHUNK;
  const int end = min(base + CHUNK, e);
  for (int i = base + threadIdx.x; i < end; i += 256) {
    int s = ei[i], d = ei[e + i];
    int p = atomicAdd(&cur[d >> 7], 1);
    ebkt[p] = ((uint)(d & 127) << 17) | (uint)s;
  }
}

__global__ __launch_bounds__(256) void bkt_deg_kernel(const uint* __restrict__ ebkt,
                                                      const int* __restrict__ boff,
                                                      int* __restrict__ deg, int n) {
  __shared__ int dl[128];
  int b = blockIdx.x;
  for (int i = threadIdx.x; i < 128; i += 256) dl[i] = 0;
  __syncthreads();
  int j1 = boff[b + 1];
  for (int j = boff[b] + threadIdx.x; j < j1; j += 256)
    atomicAdd(&dl[ebkt[j] >> 17], 1);
  __syncthreads();
  for (int i = threadIdx.x; i < 128; i += 256) {
    int node = (b << 7) + i;
    if (node < n) deg[node] = dl[i];
  }
}

__global__ __launch_bounds__(256) void bkt_fill_kernel(const uint* __restrict__ ebkt,
                                                       const int* __restrict__ boff,
                                                       const int* __restrict__ rowp,
                                                       int* __restrict__ colb, int n) {
  __shared__ int cur[128];
  int b = blockIdx.x;
  for (int i = threadIdx.x; i < 128; i += 256) {
    int node = (b << 7) + i;
    cur[i] = (node < n) ? rowp[node] : 0;
  }
  __syncthreads();
  int j1 = boff[b + 1];
  for (int j = boff[b] + threadIdx.x; j < j1; j += 256) {
    uint v = ebkt[j];
    int p = atomicAdd(&cur[v >> 17], 1);
    colb[p] = (int)(v & 0x1FFFFu);
  }
}

// ---------------- node-degree scan (rowp) ----------------
__global__ void scan1_kernel(const int* __restrict__ deg, int* __restrict__ outp,
                             int* __restrict__ partial, int n) {
  __shared__ int sd[256];
  int t = threadIdx.x;
  int base = blockIdx.x * 1024 + t * 4;
  int v0 = base + 0 < n ? deg[base + 0] : 0;
  int v1 = base + 1 < n ? deg[base + 1] : 0;
  int v2 = base + 2 < n ? deg[base + 2] : 0;
  int v3 = base + 3 < n ? deg[base + 3] : 0;
  int ts = v0 + v1 + v2 + v3;
  sd[t] = ts; __syncthreads();
  for (int off = 1; off < 256; off <<= 1) {
    int u = (t >= off) ? sd[t - off] : 0;
    __syncthreads();
    sd[t] += u;
    __syncthreads();
  }
  int excl = sd[t] - ts;
  if (base + 0 < n) outp[base + 0] = excl;
  if (base + 1 < n) outp[base + 1] = excl + v0;
  if (base + 2 < n) outp[base + 2] = excl + v0 + v1;
  if (base + 3 < n) outp[base + 3] = excl + v0 + v1 + v2;
  if (t == 255) partial[blockIdx.x] = sd[255];
}

__global__ void scan2_kernel(int* __restrict__ partial, int nb) {
  __shared__ int sd[256];
  int t = threadIdx.x;
  int v = t < nb ? partial[t] : 0;
  sd[t] = v; __syncthreads();
  for (int off = 1; off < 256; off <<= 1) {
    int u = (t >= off) ? sd[t - off] : 0;
    __syncthreads();
    sd[t] += u;
    __syncthreads();
  }
  if (t < nb) partial[t] = sd[t] - v;  // exclusive block offsets
}

__global__ void scan3_kernel(int* __restrict__ rowp, const int* __restrict__ partial,
                             int n, int e) {
  int i = blockIdx.x * 256 + threadIdx.x;
  if (i == 0) rowp[n] = e;
  if (i < n) rowp[i] += partial[i >> 10];
}

// ---------------- prep ----------------
__global__ void bnprep_kernel(const float* b1, const float* g1, const float* be1,
                              const float* m1, const float* v1,
                              const float* bL, const float* gL, const float* beL,
                              const float* mL, const float* vL,
                              float* __restrict__ sc, float* __restrict__ tc) {
  int i = blockIdx.x * 256 + threadIdx.x;
  if (i >= 4 * 128) return;
  int layer = i >> 7, c = i & 127;
  float b, g, be, m, v;
  if (layer == 0) { b = b1[c]; g = g1[c]; be = be1[c]; m = m1[c]; v = v1[c]; }
  else { int o = (layer - 1) * 128 + c; b = bL[o]; g = gL[o]; be = beL[o]; m = mL[o]; v = vL[o]; }
  float s = g * rsqrtf(v + 1e-5f);
  sc[i] = s;
  tc[i] = (b - m) * s + be;
}

// transpose fp32 weights -> bf16 Wt (M x K row-major)
__global__ void wtprep_kernel(const float* __restrict__ W1, const float* __restrict__ WL,
                              const float* __restrict__ Wc1, const float* __restrict__ Wcl,
                              ushort* __restrict__ wt1, ushort* __restrict__ wtL,
                              ushort* __restrict__ wtc1, ushort* __restrict__ wtcl) {
  int i = blockIdx.x * 256 + threadIdx.x;
  if (i < 8192) {                                      // W1: 64x128 -> 128x64
    int m = i >> 6, k = i & 63;
    wt1[i] = f2bf(W1[k * 128 + m]);
  } else if (i < 8192 + 49152) {                       // WL: 3 x 128x128
    int j = i - 8192;
    int l = j >> 14, r = j & 16383, m = r >> 7, k = r & 127;
    wtL[j] = f2bf(WL[l * 16384 + k * 128 + m]);
  } else if (i < 8192 + 49152 + 32768) {               // Wc1: 128x256 -> 256x128
    int j = i - (8192 + 49152);
    int m = j >> 7, k = j & 127;
    wtc1[j] = f2bf(Wc1[k * 256 + m]);
  } else if (i < 8192 + 49152 + 32768 + 131072) {      // Wcl: 2 x 256x256
    int j = i - (8192 + 49152 + 32768);
    int l = j >> 16, r = j & 65535, m = r >> 8, k = r & 255;
    wtcl[j] = f2bf(Wcl[l * 65536 + k * 256 + m]);
  }
}

// x fp32 [N][64] -> e5m2 [N][64]
__global__ void xconv_kernel(const float* __restrict__ x, uchar* __restrict__ x8, int n4) {
  int i = blockIdx.x * 256 + threadIdx.x;
  if (i < n4) {
    float4 v = ((const float4*)x)[i];
    uint w = enc_pk<false>(v.x, v.y, 0u);
    w = enc_pk<true>(v.z, v.w, w);
    ((uint*)x8)[i] = w;
  }
}

// ---------------- aggregation v7: fp8 gather, R16 MLP shape ------------------
template<int C>
__global__ __launch_bounds__(256) void agg_kernel(
    const uchar* __restrict__ hb8, const int* __restrict__ rowp,
    const int* __restrict__ colb, const float* __restrict__ ep,
    ushort* __restrict__ zout, int n)
{
  constexpr int LPE = C / 8;     // lanes per edge (16 for C=128, 8 for C=64)
  constexpr int EPR = 64 / LPE;  // edges per round (4 or 8)
  const int lane = threadIdx.x & 63;
  const int node = blockIdx.x * 4 + (threadIdx.x >> 6);
  if (node >= n) return;
  const float e1 = 1.0f + ep[0];
  const int lo = lane & (LPE - 1);
  const int g  = lane / LPE;
  int j0 = rowp[node], jend = rowp[node + 1];

  float a0 = 0.f, a1 = 0.f, a2 = 0.f, a3 = 0.f,
        a4 = 0.f, a5 = 0.f, a6 = 0.f, a7 = 0.f;

  for (; j0 < jend; j0 += 64) {
    int cnt = jend - j0; if (cnt > 64) cnt = 64;
    int myn = (lane < cnt) ? colb[j0 + lane] : 0;
    int rounds = (cnt + EPR - 1) / EPR;
    #pragma unroll 4
    for (int r = 0; r < rounds; ++r) {
      int e = r * EPR + g;
      int u = __shfl(myn, e);          // all lanes active for the shuffle
      if (e < cnt) {
        const uint2 v = *(const uint2*)(hb8 + (size_t)u * C + lo * 8);
        f32x2 p;
        p = dec_pk<false>(v.x); a0 += p.x; a1 += p.y;
        p = dec_pk<true >(v.x); a2 += p.x; a3 += p.y;
        p = dec_pk<false>(v.y); a4 += p.x; a5 += p.y;
        p = dec_pk<true >(v.y); a6 += p.x; a7 += p.y;
      }
    }
  }

  // combine group partials
  #pragma unroll
  for (int s = LPE; s < 64; s <<= 1) {
    a0 += __shfl_xor(a0, s); a1 += __shfl_xor(a1, s);
    a2 += __shfl_xor(a2, s); a3 += __shfl_xor(a3, s);
    a4 += __shfl_xor(a4, s); a5 += __shfl_xor(a5, s);
    a6 += __shfl_xor(a6, s); a7 += __shfl_xor(a7, s);
  }

  if (g == 0) {
    const uint2 d = *(const uint2*)(hb8 + (size_t)node * C + lo * 8);
    float sv[8];
    f32x2 p;
    p = dec_pk<false>(d.x); sv[0] = p.x; sv[1] = p.y;
    p = dec_pk<true >(d.x); sv[2] = p.x; sv[3] = p.y;
    p = dec_pk<false>(d.y); sv[4] = p.x; sv[5] = p.y;
    p = dec_pk<true >(d.y); sv[6] = p.x; sv[7] = p.y;
    ushort r[8];
    r[0] = f2bf(e1 * sv[0] + a0); r[1] = f2bf(e1 * sv[1] + a1);
    r[2] = f2bf(e1 * sv[2] + a2); r[3] = f2bf(e1 * sv[3] + a3);
    r[4] = f2bf(e1 * sv[4] + a4); r[5] = f2bf(e1 * sv[5] + a5);
    r[6] = f2bf(e1 * sv[6] + a6); r[7] = f2bf(e1 * sv[7] + a7);
    *(uint4*)(zout + (size_t)node * C + lo * 8) = *(uint4*)&r[0];
  }
}

// ---------------- GEMM v5 (GIN layers): global_load_lds staging --------------
// F8OUT: write e5m2 gather table (consumed by agg) instead of bf16.
template<int K, int M, int ACT, bool BN, bool F8OUT>
__global__ __launch_bounds__(256) void gemm_kernel(
    const ushort* __restrict__ xin,   // N x K  bf16
    const ushort* __restrict__ wt,    // M x K  bf16 (row-major)
    const float*  __restrict__ sc,
    const float*  __restrict__ tc,
    void* __restrict__ hout,          // N x M  bf16 or e5m2
    int n)
{
  constexpr int KS = 64;
  __shared__ ushort ldsW[128 * KS];   // 16 KiB
  __shared__ ushort ldsX[128 * KS];   // 16 KiB
  const int tid = threadIdx.x;
  const int wave = tid >> 6, lane = tid & 63;
  const int lr = lane & 15, lg = lane >> 4;
  const int n0 = blockIdx.x * 128;
  const int mB = blockIdx.y * 128;

  f32x4 acc[8][2];
  #pragma unroll
  for (int r = 0; r < 8; ++r) {
    acc[r][0] = (f32x4){0.f, 0.f, 0.f, 0.f};
    acc[r][1] = (f32x4){0.f, 0.f, 0.f, 0.f};
  }

  #pragma unroll
  for (int s = 0; s < K / KS; ++s) {
    if (s) __syncthreads();           // previous reads done before overwrite
    #pragma unroll
    for (int i = 0; i < 4; ++i) {
      const int ub = wave * 4096 + i * 1024;       // wave-uniform lds byte base
      const int a  = ub + lane * 16;               // this lane's lds byte
      const int m  = a >> 7;                       // row (128B rows)
      const int o  = (a & 127) ^ ((m & 7) << 4);   // pre-swizzled src offset
      gload_lds16((const char*)wt + ((size_t)(mB + m) * K) * 2 + s * 128 + o,
                  (char*)ldsW + ub);
      int nd = n0 + m; if (nd >= n) nd = n - 1;
      gload_lds16((const char*)xin + ((size_t)nd * K) * 2 + s * 128 + o,
                  (char*)ldsX + ub);
    }
    asm volatile("s_waitcnt vmcnt(0)" ::: "memory");
    __syncthreads();
    #pragma unroll
    for (int k0 = 0; k0 < KS; k0 += 32) {
      const int kb = (k0 + lg * 8) * 2;  // byte offset of this lane's 16B in a row
      bf16x8 wf0, wf1;
      {
        int m = wave * 32 + lr;
        wf0 = __builtin_bit_cast(bf16x8,
              *(const uint4*)((const char*)ldsW + ((m * 128 + kb) ^ ((m & 7) << 4))));
        m += 16;
        wf1 = __builtin_bit_cast(bf16x8,
              *(const uint4*)((const char*)ldsW + ((m * 128 + kb) ^ ((m & 7) << 4))));
      }
      #pragma unroll
      for (int r = 0; r < 8; ++r) {
        int xr = r * 16 + lr;
        bf16x8 xf = __builtin_bit_cast(bf16x8,
              *(const uint4*)((const char*)ldsX + ((xr * 128 + kb) ^ ((xr & 7) << 4))));
        acc[r][0] = __builtin_amdgcn_mfma_f32_16x16x32_bf16(wf0, xf, acc[r][0], 0, 0, 0);
        acc[r][1] = __builtin_amdgcn_mfma_f32_16x16x32_bf16(wf1, xf, acc[r][1], 0, 0, 0);
      }
    }
  }

  #pragma unroll
  for (int ct = 0; ct < 2; ++ct) {
    const int c0 = mB + wave * 32 + ct * 16 + lg * 4;
    float4 sv;
    if constexpr (BN) sv = *(const float4*)(sc + c0);
    else sv = make_float4(1.f, 1.f, 1.f, 1.f);
    const float4 tv = *(const float4*)(tc + c0);
    #pragma unroll
    for (int r = 0; r < 8; ++r) {
      const int node = n0 + r * 16 + lr;
      if (node < n) {
        const f32x4 a = acc[r][ct];
        float v0 = actf<ACT>(a[0] * sv.x + tv.x);
        float v1 = actf<ACT>(a[1] * sv.y + tv.y);
        float v2 = actf<ACT>(a[2] * sv.z + tv.z);
        float v3 = actf<ACT>(a[3] * sv.w + tv.w);
        if constexpr (F8OUT) {
          uint wv = enc_pk<false>(v0, v1, 0u);
          wv = enc_pk<true>(v2, v3, wv);
          *(uint*)((uchar*)hout + (size_t)node * M + c0) = wv;
        } else {
          ushort4 o;
          o.x = f2bf(v0); o.y = f2bf(v1); o.z = f2bf(v2); o.w = f2bf(v3);
          *(ushort4*)((ushort*)hout + (size_t)node * M + c0) = o;
        }
      }
    }
  }
}

// ---------------- fused classifier: c1 + c2 + c3 + Wf-dot + sigmoid ----------
// block = 128 nodes, 1024 threads (16 waves, 16 out-ch each). Dynamic LDS 144KB:
//   ldsW0[32KB] | ldsW1[32KB] | ldsH[64KB: 4 K-slabs x 128 nodes x 64ch] | ldsX[16KB]
__global__ __launch_bounds__(1024, 4) void cls_kernel(
    const ushort* __restrict__ xin,   // N x 128 bf16 (GIN output)
    const ushort* __restrict__ wc1,   // 256 x 128 bf16
    const float*  __restrict__ bc1,   // 256
    const ushort* __restrict__ wcl,   // 2 x 256 x 256 bf16
    const float*  __restrict__ bcl,   // 2 x 256
    const float*  __restrict__ wfv,   // 256
    const float*  __restrict__ bfp,   // 1
    float* __restrict__ out, int n)
{
  extern __shared__ char lds[];
  char* ldsW0 = lds;
  char* ldsW1 = lds + 32768;
  char* ldsH  = lds + 65536;
  char* ldsX  = lds + 131072;
  const int tid = threadIdx.x;
  const int wave = tid >> 6, lane = tid & 63;
  const int lr = lane & 15, lg = lane >> 4;
  const int n0 = blockIdx.x * 128;

  f32x4 acc[8];

  // stage a 256-row x 64-ch W slab (32KB); each of 16 waves covers 2KB
  auto stageW = [&](const ushort* wsrc, int K2, int s, char* dst) {
    #pragma unroll
    for (int i = 0; i < 2; ++i) {
      const int ub = wave * 2048 + i * 1024;
      const int a = ub + lane * 16;
      const int m = a >> 7;
      const int o = (a & 127) ^ ((m & 7) << 4);
      gload_lds16((const char*)wsrc + (size_t)m * K2 * 2 + s * 128 + o, dst + ub);
    }
  };
  // stage 128-node x 64-ch X slab (16KB); each wave covers 1KB
  auto stageX = [&](int s) {
    const int ub = wave * 1024;
    const int a = ub + lane * 16;
    const int m = a >> 7;
    const int o = (a & 127) ^ ((m & 7) << 4);
    int nd = n0 + m; if (nd >= n) nd = n - 1;
    gload_lds16((const char*)xin + (size_t)nd * 128 * 2 + s * 128 + o, ldsX + ub);
  };
  // one K=64 slab of MFMAs: W rows wave*16+lr, X rows rowOff+r*16+lr
  auto mfma_slab = [&](const char* wbuf, const char* xbase, int rowOff) {
    #pragma unroll
    for (int k0 = 0; k0 < 64; k0 += 32) {
      const int kb = (k0 + lg * 8) * 2;
      int m = wave * 16 + lr;
      bf16x8 wfr = __builtin_bit_cast(bf16x8,
                   *(const uint4*)(wbuf + ((m * 128 + kb) ^ ((m & 7) << 4))));
      #pragma unroll
      for (int r = 0; r < 8; ++r) {
        int xr = rowOff + r * 16 + lr;
        bf16x8 xf = __builtin_bit_cast(bf16x8,
                    *(const uint4*)(xbase + ((xr * 128 + kb) ^ ((xr & 7) << 4))));
        acc[r] = __builtin_amdgcn_mfma_f32_16x16x32_bf16(wfr, xf, acc[r], 0, 0, 0);
      }
    }
  };
  auto zacc = [&]() {
    #pragma unroll
    for (int r = 0; r < 8; ++r) acc[r] = (f32x4){0.f, 0.f, 0.f, 0.f};
  };
  // write this wave's 16ch x 128node tile into ldsH (K-slab layout)
  auto writeH = [&](const float* bias, bool act) {
    const int c0 = wave * 16 + lg * 4;               // global channel 0..255
    const float4 bv = *(const float4*)(bias + c0);
    const int slab = c0 >> 6, cis = (c0 & 63) * 2;   // K-slab, byte col in slab
    #pragma unroll
    for (int r = 0; r < 8; ++r) {
      const int rowH = slab * 128 + r * 16 + lr;
      const f32x4 a = acc[r];
      ushort4 o;
      if (act) {
        o.x = f2bf(actf<1>(a[0] + bv.x)); o.y = f2bf(actf<1>(a[1] + bv.y));
        o.z = f2bf(actf<1>(a[2] + bv.z)); o.w = f2bf(actf<1>(a[3] + bv.w));
      } else {
        o.x = f2bf(a[0] + bv.x); o.y = f2bf(a[1] + bv.y);
        o.z = f2bf(a[2] + bv.z); o.w = f2bf(a[3] + bv.w);
      }
      *(ushort4*)(ldsH + ((rowH * 128 + cis) ^ ((rowH & 7) << 4))) = o;
    }
  };

  // ---- c1: h1 = X(128) @ Wc1^T + bc1 ----
  zacc();
  #pragma unroll
  for (int s = 0; s < 2; ++s) {
    if (s) __syncthreads();
    stageX(s);
    stageW(wc1, 128, s, ldsW0);
    asm volatile("s_waitcnt vmcnt(0)" ::: "memory");
    __syncthreads();
    mfma_slab(ldsW0, ldsX, 0);
  }
  __syncthreads();
  writeH(bc1, false);                               // h1 -> ldsH

  // ---- c2 (g=0): h2 = lrelu(h1 @ Wcl0^T + bcl0) -> ldsH
  // ---- c3 (g=1): logit = lrelu(h2 @ Wcl1^T + bcl1) . Wf + bf -> sigmoid
  for (int g = 0; g < 2; ++g) {
    const ushort* Wg = wcl + g * 65536;
    const float*  bg = bcl + g * 256;
    zacc();
    __syncthreads();                                // h-writes visible; ldsW free
    stageW(Wg, 256, 0, ldsW0);
    #pragma unroll
    for (int s = 0; s < 4; ++s) {
      char* cur = (s & 1) ? ldsW1 : ldsW0;
      char* nxt = (s & 1) ? ldsW0 : ldsW1;
      if (s + 1 < 4) {
        stageW(Wg, 256, s + 1, nxt);
        asm volatile("s_waitcnt vmcnt(2)" ::: "memory");
      } else {
        asm volatile("s_waitcnt vmcnt(0)" ::: "memory");
      }
      __syncthreads();
      mfma_slab(cur, ldsH, s * 128);
      __syncthreads();
    }
    if (g == 0) {
      writeH(bg, true);                             // h2 -> ldsH (in place)
    } else {
      float* red = (float*)ldsX;                    // 16 waves x 128 nodes (8KB)
      #pragma unroll
      for (int r = 0; r < 8; ++r) {
        const int c0 = wave * 16 + lg * 4;
        const float4 bv = *(const float4*)(bg + c0);
        const float4 wv = *(const float4*)(wfv + c0);
        const f32x4 a = acc[r];
        float p = actf<1>(a[0] + bv.x) * wv.x + actf<1>(a[1] + bv.y) * wv.y
                + actf<1>(a[2] + bv.z) * wv.z + actf<1>(a[3] + bv.w) * wv.w;
        p += __shfl_xor(p, 16);
        p += __shfl_xor(p, 32);
        if (lg == 0) red[wave * 128 + r * 16 + lr] = p;
      }
      __syncthreads();
      if (tid < 128) {
        const int nd = n0 + tid;
        if (nd < n) {
          float logit = bfp[0];
          #pragma unroll
          for (int w = 0; w < 16; ++w) logit += red[w * 128 + tid];
          out[nd] = 1.f / (1.f + expf(-logit));
        }
      }
    }
  }
}

// ---------------- launch ----------------
extern "C" void kernel_launch(void* const* d_in, const int* in_sizes, int n_in,
                              void* d_out, int out_size, void* d_ws, size_t ws_size,
                              hipStream_t stream)
{
  const float* x    = (const float*)d_in[0];
  const int*   ei   = (const int*)d_in[1];
  const float* eps1 = (const float*)d_in[3];
  const float* W1   = (const float*)d_in[4];
  const float* b1   = (const float*)d_in[5];
  const float* g1   = (const float*)d_in[6];
  const float* be1  = (const float*)d_in[7];
  const float* m1   = (const float*)d_in[8];
  const float* v1   = (const float*)d_in[9];
  const float* epsL = (const float*)d_in[10];
  const float* WL   = (const float*)d_in[11];
  const float* bL   = (const float*)d_in[12];
  const float* gL   = (const float*)d_in[13];
  const float* beL  = (const float*)d_in[14];
  const float* mL   = (const float*)d_in[15];
  const float* vL   = (const float*)d_in[16];
  const float* Wc1  = (const float*)d_in[17];
  const float* bc1  = (const float*)d_in[18];
  const float* Wcl  = (const float*)d_in[19];
  const float* bcl  = (const float*)d_in[20];
  const float* Wf   = (const float*)d_in[21];
  const float* bfp  = (const float*)d_in[22];
  float* out = (float*)d_out;

  char* w = (char*)d_ws;
  size_t off = 0;
  auto alloc = [&](size_t bytes) {
    char* p = w + off;
    off += (bytes + 255) & ~(size_t)255;
    return p;
  };
  ushort* bufA   = (ushort*)alloc((size_t)NN * 256 * 2);   // 51.2 MB (bf16)
  ushort* bufB   = (ushort*)alloc((size_t)NN * 256 * 2);   // 51.2 MB (bf16 zin)
  uchar*  h8     = (uchar*)alloc((size_t)NN * 128);        // 12.8 MB fp8 table
  int*    rowp   = (int*)alloc((NN + 1) * 4);
  int*    deg    = (int*)alloc(NN * 4);
  int*    colb   = (int*)alloc((size_t)EE * 4);
  uint*   ebkt   = (uint*)alloc((size_t)EE * 4);
  int*    hist   = (int*)alloc((size_t)NCH * NBK * 4);     // 613 KB
  int*    bh     = (int*)alloc(NBK * 4);
  int*    boff   = (int*)alloc((NBK + 1) * 4);
  int*    partial= (int*)alloc(1024);
  ushort* wt1    = (ushort*)alloc(8192 * 2);
  ushort* wtL    = (ushort*)alloc(49152 * 2);
  ushort* wtc1   = (ushort*)alloc(32768 * 2);
  ushort* wtcl   = (ushort*)alloc(131072 * 2);
  float*  sc     = (float*)alloc(512 * 4);
  float*  tc     = (float*)alloc(512 * 4);
  (void)ws_size; (void)in_sizes; (void)n_in; (void)out_size;

  // multi-split CSR build (by dst), no global atomics in the scatter
  hipMemsetAsync(bh, 0, NBK * 4, stream);
  ms_hist_kernel<<<NCH, 256, 0, stream>>>(ei, hist, bh, EE);
  bkt_scan_kernel<<<1, 256, 0, stream>>>(bh, boff, EE);
  ms_offs_kernel<<<(NBK + 255) / 256, 256, 0, stream>>>(hist, boff);
  ms_scatter_kernel<<<NCH, 256, 0, stream>>>(ei, hist, ebkt, EE);
  bkt_deg_kernel<<<NBK, 256, 0, stream>>>(ebkt, boff, deg, NN);
  scan1_kernel<<<98, 256, 0, stream>>>(deg, rowp, partial, NN);
  scan2_kernel<<<1, 256, 0, stream>>>(partial, 98);
  scan3_kernel<<<(NN + 255) / 256, 256, 0, stream>>>(rowp, partial, NN, EE);
  bkt_fill_kernel<<<NBK, 256, 0, stream>>>(ebkt, boff, rowp, colb, NN);

  // prep
  bnprep_kernel<<<2, 256, 0, stream>>>(b1, g1, be1, m1, v1, bL, gL, beL, mL, vL, sc, tc);
  wtprep_kernel<<<864, 256, 0, stream>>>(W1, WL, Wc1, Wcl, wt1, wtL, wtc1, wtcl);
  xconv_kernel<<<(NN * CIN / 4 + 255) / 256, 256, 0, stream>>>(x, h8, NN * CIN / 4);

  const int GB = (NN + 127) / 128;   // 782 node-tiles

  // GIN layer 1 (64 -> 128), double lrelu; writes fp8 table
  agg_kernel<64><<<25000, 256, 0, stream>>>(h8, rowp, colb, eps1, bufB, NN);
  gemm_kernel<64, 128, 2, true, true><<<dim3(GB, 1), 256, 0, stream>>>(bufB, wt1, sc, tc, h8, NN);
  // GIN layers 2-3 (128 -> 128), double lrelu; write fp8 table
  for (int i = 0; i < 2; ++i) {
    agg_kernel<128><<<25000, 256, 0, stream>>>(h8, rowp, colb, epsL + i, bufB, NN);
    gemm_kernel<128, 128, 2, true, true><<<dim3(GB, 1), 256, 0, stream>>>(
        bufB, wtL + i * 16384, sc + 128 * (i + 1), tc + 128 * (i + 1), h8, NN);
  }
  // GIN layer 4: bf16 output for the fused classifier
  agg_kernel<128><<<25000, 256, 0, stream>>>(h8, rowp, colb, epsL + 2, bufB, NN);
  gemm_kernel<128, 128, 2, true, false><<<dim3(GB, 1), 256, 0, stream>>>(
      bufB, wtL + 2 * 16384, sc + 128 * 3, tc + 128 * 3, bufA, NN);
  // fused classifier + final (reads bufA, writes out)
  hipFuncSetAttribute(reinterpret_cast<const void*>(cls_kernel),
                      hipFuncAttributeMaxDynamicSharedMemorySize, 147456);
  cls_kernel<<<GB, 1024, 147456, stream>>>(bufA, wtc1, bc1, wtcl, bcl, Wf, bfp, out, NN);
}

// Round 21
// 413.646 us; speedup vs baseline: 1.0209x; 1.0209x over previous
//
#include <hip/hip_runtime.h>
#include <hip/hip_fp16.h>
#include <stdint.h>

// ---------------------------------------------------------------------------
// GIN (4 layers, CSR gather aggregation) + MLP classifier, bf16 MFMA GEMMs.
// R21: revert cls_kernel to the R16/R18 512-thread config (69.5us, no spill).
//   Both 16-wave variants (R19 plain, R20 __launch_bounds__(1024,4)) spilled
//   identically (VGPR pinned at 64, WRITE 30.6MB scratch) -> 4 waves/SIMD at
//   144KB LDS is not reachable through the compiler; 2 waves/SIMD is the
//   measured optimum. agg stays fp8 + R16 MLP shape (~64us convergent floor).
// ---------------------------------------------------------------------------

#define NN  100000
#define EE  1600000
#define CIN 64
#define CC  128
#define NBK 782              // ceil(NN / 128) buckets, bucket = dst >> 7
#define CHUNK 8192           // edges per multi-split block
#define NCH 196              // ceil(EE / CHUNK)

typedef __attribute__((ext_vector_type(8))) __bf16 bf16x8;
typedef __attribute__((ext_vector_type(4))) float  f32x4;
typedef __attribute__((ext_vector_type(2))) float  f32x2;

__device__ __forceinline__ float bf2f(uint32_t u) { return __uint_as_float(u << 16); }
__device__ __forceinline__ float bf2f_hi(uint32_t u) { return __uint_as_float(u & 0xffff0000u); }
__device__ __forceinline__ ushort f2bf(float f) {          // RNE f32 -> bf16
  uint32_t u = __float_as_uint(f);
  u += 0x7fffu + ((u >> 16) & 1u);
  return (ushort)(u >> 16);
}

#if __has_builtin(__builtin_amdgcn_cvt_pk_f32_bf8) && __has_builtin(__builtin_amdgcn_cvt_pk_bf8_f32)
#define F8_HW 1
#endif

// decode 2 e5m2 bytes (word HI of dword d) -> 2 f32
template<bool HI> __device__ __forceinline__ f32x2 dec_pk(uint d) {
#ifdef F8_HW
  return __builtin_amdgcn_cvt_pk_f32_bf8((int)d, HI);
#else
  uint w = HI ? (d >> 16) : d;
  f32x2 r;
  uint b0 = w & 0xFFu, b1 = (w >> 8) & 0xFFu;
  r.x = __uint_as_float(((b0 & 0x80u) << 24) | ((b0 & 0x7Fu) << 21)) * 0x1.0p112f;
  r.y = __uint_as_float(((b1 & 0x80u) << 24) | ((b1 & 0x7Fu) << 21)) * 0x1.0p112f;
  return r;
#endif
}
// encode 2 f32 -> 2 e5m2 bytes into word HI of old
template<bool HI> __device__ __forceinline__ uint enc_pk(float a, float b, uint old) {
#ifdef F8_HW
  return (uint)__builtin_amdgcn_cvt_pk_bf8_f32(a, b, (int)old, HI);
#else
  ushort ha = __half_as_ushort(__float2half(a));
  ushort hb = __half_as_ushort(__float2half(b));
  ha = (ushort)(ha + 0x7F + ((ha >> 8) & 1));
  hb = (ushort)(hb + 0x7F + ((hb >> 8) & 1));
  uint two = (uint)(ha >> 8) | ((uint)(hb >> 8) << 8);
  return HI ? ((old & 0x0000FFFFu) | (two << 16)) : ((old & 0xFFFF0000u) | two);
#endif
}

template<int ACT> __device__ __forceinline__ float actf(float z) {
  if constexpr (ACT == 1) return z >= 0.f ? z : 0.01f * z;       // lrelu
  else if constexpr (ACT == 2) return z >= 0.f ? z : 1e-4f * z;  // lrelu(lrelu)
  else return z;
}

// async global->LDS, 16B per lane; lds base must be wave-uniform
__device__ __forceinline__ void gload_lds16(const void* g, void* l) {
  __builtin_amdgcn_global_load_lds(
      (const __attribute__((address_space(1))) void*)g,
      (__attribute__((address_space(3))) void*)l, 16, 0, 0);
}

// ---------------- multi-split CSR build ----------------
__global__ __launch_bounds__(256) void ms_hist_kernel(const int* __restrict__ ei,
                                                      int* __restrict__ hist,
                                                      int* __restrict__ bh, int e) {
  __shared__ int h[NBK];
  for (int i = threadIdx.x; i < NBK; i += 256) h[i] = 0;
  __syncthreads();
  const int base = blockIdx.x * CHUNK;
  const int end = min(base + CHUNK, e);
  for (int i = base + threadIdx.x; i < end; i += 256)
    atomicAdd(&h[ei[e + i] >> 7], 1);
  __syncthreads();
  for (int i = threadIdx.x; i < NBK; i += 256) {
    hist[blockIdx.x * NBK + i] = h[i];
    if (h[i]) atomicAdd(&bh[i], h[i]);
  }
}

__global__ __launch_bounds__(256) void bkt_scan_kernel(const int* __restrict__ bh,
                                                       int* __restrict__ boff, int e) {
  __shared__ int sd[256];
  int t = threadIdx.x;
  int base = t * 4;
  int v0 = base + 0 < NBK ? bh[base + 0] : 0;
  int v1 = base + 1 < NBK ? bh[base + 1] : 0;
  int v2 = base + 2 < NBK ? bh[base + 2] : 0;
  int v3 = base + 3 < NBK ? bh[base + 3] : 0;
  int ts = v0 + v1 + v2 + v3;
  sd[t] = ts; __syncthreads();
  for (int off = 1; off < 256; off <<= 1) {
    int u = (t >= off) ? sd[t - off] : 0;
    __syncthreads();
    sd[t] += u;
    __syncthreads();
  }
  int excl = sd[t] - ts;
  if (base + 0 < NBK) boff[base + 0] = excl;
  if (base + 1 < NBK) boff[base + 1] = excl + v0;
  if (base + 2 < NBK) boff[base + 2] = excl + v0 + v1;
  if (base + 3 < NBK) boff[base + 3] = excl + v0 + v1 + v2;
  if (t == 255) boff[NBK] = e;
}

__global__ void ms_offs_kernel(int* __restrict__ hist, const int* __restrict__ boff) {
  int b = blockIdx.x * 256 + threadIdx.x;
  if (b >= NBK) return;
  int run = boff[b];
  for (int k = 0; k < NCH; ++k) {
    int t = hist[k * NBK + b];     // coalesced across b
    hist[k * NBK + b] = run;
    run += t;
  }
}

__global__ __launch_bounds__(256) void ms_scatter_kernel(const int* __restrict__ ei,
                                                         const int* __restrict__ hist,
                                                         uint* __restrict__ ebkt, int e) {
  __shared__ int cur[NBK];
  for (int i = threadIdx.x; i < NBK; i += 256) cur[i] = hist[blockIdx.x * NBK + i];
  __syncthreads();
  const int base = blockIdx.x * CHUNK;
  const int end = min(base + CHUNK, e);
  for (int i = base + threadIdx.x; i < end; i += 256) {
    int s = ei[i], d = ei[e + i];
    int p = atomicAdd(&cur[d >> 7], 1);
    ebkt[p] = ((uint)(d & 127) << 17) | (uint)s;
  }
}

__global__ __launch_bounds__(256) void bkt_deg_kernel(const uint* __restrict__ ebkt,
                                                      const int* __restrict__ boff,
                                                      int* __restrict__ deg, int n) {
  __shared__ int dl[128];
  int b = blockIdx.x;
  for (int i = threadIdx.x; i < 128; i += 256) dl[i] = 0;
  __syncthreads();
  int j1 = boff[b + 1];
  for (int j = boff[b] + threadIdx.x; j < j1; j += 256)
    atomicAdd(&dl[ebkt[j] >> 17], 1);
  __syncthreads();
  for (int i = threadIdx.x; i < 128; i += 256) {
    int node = (b << 7) + i;
    if (node < n) deg[node] = dl[i];
  }
}

__global__ __launch_bounds__(256) void bkt_fill_kernel(const uint* __restrict__ ebkt,
                                                       const int* __restrict__ boff,
                                                       const int* __restrict__ rowp,
                                                       int* __restrict__ colb, int n) {
  __shared__ int cur[128];
  int b = blockIdx.x;
  for (int i = threadIdx.x; i < 128; i += 256) {
    int node = (b << 7) + i;
    cur[i] = (node < n) ? rowp[node] : 0;
  }
  __syncthreads();
  int j1 = boff[b + 1];
  for (int j = boff[b] + threadIdx.x; j < j1; j += 256) {
    uint v = ebkt[j];
    int p = atomicAdd(&cur[v >> 17], 1);
    colb[p] = (int)(v & 0x1FFFFu);
  }
}

// ---------------- node-degree scan (rowp) ----------------
__global__ void scan1_kernel(const int* __restrict__ deg, int* __restrict__ outp,
                             int* __restrict__ partial, int n) {
  __shared__ int sd[256];
  int t = threadIdx.x;
  int base = blockIdx.x * 1024 + t * 4;
  int v0 = base + 0 < n ? deg[base + 0] : 0;
  int v1 = base + 1 < n ? deg[base + 1] : 0;
  int v2 = base + 2 < n ? deg[base + 2] : 0;
  int v3 = base + 3 < n ? deg[base + 3] : 0;
  int ts = v0 + v1 + v2 + v3;
  sd[t] = ts; __syncthreads();
  for (int off = 1; off < 256; off <<= 1) {
    int u = (t >= off) ? sd[t - off] : 0;
    __syncthreads();
    sd[t] += u;
    __syncthreads();
  }
  int excl = sd[t] - ts;
  if (base + 0 < n) outp[base + 0] = excl;
  if (base + 1 < n) outp[base + 1] = excl + v0;
  if (base + 2 < n) outp[base + 2] = excl + v0 + v1;
  if (base + 3 < n) outp[base + 3] = excl + v0 + v1 + v2;
  if (t == 255) partial[blockIdx.x] = sd[255];
}

__global__ void scan2_kernel(int* __restrict__ partial, int nb) {
  __shared__ int sd[256];
  int t = threadIdx.x;
  int v = t < nb ? partial[t] : 0;
  sd[t] = v; __syncthreads();
  for (int off = 1; off < 256; off <<= 1) {
    int u = (t >= off) ? sd[t - off] : 0;
    __syncthreads();
    sd[t] += u;
    __syncthreads();
  }
  if (t < nb) partial[t] = sd[t] - v;  // exclusive block offsets
}

__global__ void scan3_kernel(int* __restrict__ rowp, const int* __restrict__ partial,
                             int n, int e) {
  int i = blockIdx.x * 256 + threadIdx.x;
  if (i == 0) rowp[n] = e;
  if (i < n) rowp[i] += partial[i >> 10];
}

// ---------------- prep ----------------
__global__ void bnprep_kernel(const float* b1, const float* g1, const float* be1,
                              const float* m1, const float* v1,
                              const float* bL, const float* gL, const float* beL,
                              const float* mL, const float* vL,
                              float* __restrict__ sc, float* __restrict__ tc) {
  int i = blockIdx.x * 256 + threadIdx.x;
  if (i >= 4 * 128) return;
  int layer = i >> 7, c = i & 127;
  float b, g, be, m, v;
  if (layer == 0) { b = b1[c]; g = g1[c]; be = be1[c]; m = m1[c]; v = v1[c]; }
  else { int o = (layer - 1) * 128 + c; b = bL[o]; g = gL[o]; be = beL[o]; m = mL[o]; v = vL[o]; }
  float s = g * rsqrtf(v + 1e-5f);
  sc[i] = s;
  tc[i] = (b - m) * s + be;
}

// transpose fp32 weights -> bf16 Wt (M x K row-major)
__global__ void wtprep_kernel(const float* __restrict__ W1, const float* __restrict__ WL,
                              const float* __restrict__ Wc1, const float* __restrict__ Wcl,
                              ushort* __restrict__ wt1, ushort* __restrict__ wtL,
                              ushort* __restrict__ wtc1, ushort* __restrict__ wtcl) {
  int i = blockIdx.x * 256 + threadIdx.x;
  if (i < 8192) {                                      // W1: 64x128 -> 128x64
    int m = i >> 6, k = i & 63;
    wt1[i] = f2bf(W1[k * 128 + m]);
  } else if (i < 8192 + 49152) {                       // WL: 3 x 128x128
    int j = i - 8192;
    int l = j >> 14, r = j & 16383, m = r >> 7, k = r & 127;
    wtL[j] = f2bf(WL[l * 16384 + k * 128 + m]);
  } else if (i < 8192 + 49152 + 32768) {               // Wc1: 128x256 -> 256x128
    int j = i - (8192 + 49152);
    int m = j >> 7, k = j & 127;
    wtc1[j] = f2bf(Wc1[k * 256 + m]);
  } else if (i < 8192 + 49152 + 32768 + 131072) {      // Wcl: 2 x 256x256
    int j = i - (8192 + 49152 + 32768);
    int l = j >> 16, r = j & 65535, m = r >> 8, k = r & 255;
    wtcl[j] = f2bf(Wcl[l * 65536 + k * 256 + m]);
  }
}

// x fp32 [N][64] -> e5m2 [N][64]
__global__ void xconv_kernel(const float* __restrict__ x, uchar* __restrict__ x8, int n4) {
  int i = blockIdx.x * 256 + threadIdx.x;
  if (i < n4) {
    float4 v = ((const float4*)x)[i];
    uint w = enc_pk<false>(v.x, v.y, 0u);
    w = enc_pk<true>(v.z, v.w, w);
    ((uint*)x8)[i] = w;
  }
}

// ---------------- aggregation v7: fp8 gather, R16 MLP shape ------------------
template<int C>
__global__ __launch_bounds__(256) void agg_kernel(
    const uchar* __restrict__ hb8, const int* __restrict__ rowp,
    const int* __restrict__ colb, const float* __restrict__ ep,
    ushort* __restrict__ zout, int n)
{
  constexpr int LPE = C / 8;     // lanes per edge (16 for C=128, 8 for C=64)
  constexpr int EPR = 64 / LPE;  // edges per round (4 or 8)
  const int lane = threadIdx.x & 63;
  const int node = blockIdx.x * 4 + (threadIdx.x >> 6);
  if (node >= n) return;
  const float e1 = 1.0f + ep[0];
  const int lo = lane & (LPE - 1);
  const int g  = lane / LPE;
  int j0 = rowp[node], jend = rowp[node + 1];

  float a0 = 0.f, a1 = 0.f, a2 = 0.f, a3 = 0.f,
        a4 = 0.f, a5 = 0.f, a6 = 0.f, a7 = 0.f;

  for (; j0 < jend; j0 += 64) {
    int cnt = jend - j0; if (cnt > 64) cnt = 64;
    int myn = (lane < cnt) ? colb[j0 + lane] : 0;
    int rounds = (cnt + EPR - 1) / EPR;
    #pragma unroll 4
    for (int r = 0; r < rounds; ++r) {
      int e = r * EPR + g;
      int u = __shfl(myn, e);          // all lanes active for the shuffle
      if (e < cnt) {
        const uint2 v = *(const uint2*)(hb8 + (size_t)u * C + lo * 8);
        f32x2 p;
        p = dec_pk<false>(v.x); a0 += p.x; a1 += p.y;
        p = dec_pk<true >(v.x); a2 += p.x; a3 += p.y;
        p = dec_pk<false>(v.y); a4 += p.x; a5 += p.y;
        p = dec_pk<true >(v.y); a6 += p.x; a7 += p.y;
      }
    }
  }

  // combine group partials
  #pragma unroll
  for (int s = LPE; s < 64; s <<= 1) {
    a0 += __shfl_xor(a0, s); a1 += __shfl_xor(a1, s);
    a2 += __shfl_xor(a2, s); a3 += __shfl_xor(a3, s);
    a4 += __shfl_xor(a4, s); a5 += __shfl_xor(a5, s);
    a6 += __shfl_xor(a6, s); a7 += __shfl_xor(a7, s);
  }

  if (g == 0) {
    const uint2 d = *(const uint2*)(hb8 + (size_t)node * C + lo * 8);
    float sv[8];
    f32x2 p;
    p = dec_pk<false>(d.x); sv[0] = p.x; sv[1] = p.y;
    p = dec_pk<true >(d.x); sv[2] = p.x; sv[3] = p.y;
    p = dec_pk<false>(d.y); sv[4] = p.x; sv[5] = p.y;
    p = dec_pk<true >(d.y); sv[6] = p.x; sv[7] = p.y;
    ushort r[8];
    r[0] = f2bf(e1 * sv[0] + a0); r[1] = f2bf(e1 * sv[1] + a1);
    r[2] = f2bf(e1 * sv[2] + a2); r[3] = f2bf(e1 * sv[3] + a3);
    r[4] = f2bf(e1 * sv[4] + a4); r[5] = f2bf(e1 * sv[5] + a5);
    r[6] = f2bf(e1 * sv[6] + a6); r[7] = f2bf(e1 * sv[7] + a7);
    *(uint4*)(zout + (size_t)node * C + lo * 8) = *(uint4*)&r[0];
  }
}

// ---------------- GEMM v5 (GIN layers): global_load_lds staging --------------
// F8OUT: write e5m2 gather table (consumed by agg) instead of bf16.
template<int K, int M, int ACT, bool BN, bool F8OUT>
__global__ __launch_bounds__(256) void gemm_kernel(
    const ushort* __restrict__ xin,   // N x K  bf16
    const ushort* __restrict__ wt,    // M x K  bf16 (row-major)
    const float*  __restrict__ sc,
    const float*  __restrict__ tc,
    void* __restrict__ hout,          // N x M  bf16 or e5m2
    int n)
{
  constexpr int KS = 64;
  __shared__ ushort ldsW[128 * KS];   // 16 KiB
  __shared__ ushort ldsX[128 * KS];   // 16 KiB
  const int tid = threadIdx.x;
  const int wave = tid >> 6, lane = tid & 63;
  const int lr = lane & 15, lg = lane >> 4;
  const int n0 = blockIdx.x * 128;
  const int mB = blockIdx.y * 128;

  f32x4 acc[8][2];
  #pragma unroll
  for (int r = 0; r < 8; ++r) {
    acc[r][0] = (f32x4){0.f, 0.f, 0.f, 0.f};
    acc[r][1] = (f32x4){0.f, 0.f, 0.f, 0.f};
  }

  #pragma unroll
  for (int s = 0; s < K / KS; ++s) {
    if (s) __syncthreads();           // previous reads done before overwrite
    #pragma unroll
    for (int i = 0; i < 4; ++i) {
      const int ub = wave * 4096 + i * 1024;       // wave-uniform lds byte base
      const int a  = ub + lane * 16;               // this lane's lds byte
      const int m  = a >> 7;                       // row (128B rows)
      const int o  = (a & 127) ^ ((m & 7) << 4);   // pre-swizzled src offset
      gload_lds16((const char*)wt + ((size_t)(mB + m) * K) * 2 + s * 128 + o,
                  (char*)ldsW + ub);
      int nd = n0 + m; if (nd >= n) nd = n - 1;
      gload_lds16((const char*)xin + ((size_t)nd * K) * 2 + s * 128 + o,
                  (char*)ldsX + ub);
    }
    asm volatile("s_waitcnt vmcnt(0)" ::: "memory");
    __syncthreads();
    #pragma unroll
    for (int k0 = 0; k0 < KS; k0 += 32) {
      const int kb = (k0 + lg * 8) * 2;  // byte offset of this lane's 16B in a row
      bf16x8 wf0, wf1;
      {
        int m = wave * 32 + lr;
        wf0 = __builtin_bit_cast(bf16x8,
              *(const uint4*)((const char*)ldsW + ((m * 128 + kb) ^ ((m & 7) << 4))));
        m += 16;
        wf1 = __builtin_bit_cast(bf16x8,
              *(const uint4*)((const char*)ldsW + ((m * 128 + kb) ^ ((m & 7) << 4))));
      }
      #pragma unroll
      for (int r = 0; r < 8; ++r) {
        int xr = r * 16 + lr;
        bf16x8 xf = __builtin_bit_cast(bf16x8,
              *(const uint4*)((const char*)ldsX + ((xr * 128 + kb) ^ ((xr & 7) << 4))));
        acc[r][0] = __builtin_amdgcn_mfma_f32_16x16x32_bf16(wf0, xf, acc[r][0], 0, 0, 0);
        acc[r][1] = __builtin_amdgcn_mfma_f32_16x16x32_bf16(wf1, xf, acc[r][1], 0, 0, 0);
      }
    }
  }

  #pragma unroll
  for (int ct = 0; ct < 2; ++ct) {
    const int c0 = mB + wave * 32 + ct * 16 + lg * 4;
    float4 sv;
    if constexpr (BN) sv = *(const float4*)(sc + c0);
    else sv = make_float4(1.f, 1.f, 1.f, 1.f);
    const float4 tv = *(const float4*)(tc + c0);
    #pragma unroll
    for (int r = 0; r < 8; ++r) {
      const int node = n0 + r * 16 + lr;
      if (node < n) {
        const f32x4 a = acc[r][ct];
        float v0 = actf<ACT>(a[0] * sv.x + tv.x);
        float v1 = actf<ACT>(a[1] * sv.y + tv.y);
        float v2 = actf<ACT>(a[2] * sv.z + tv.z);
        float v3 = actf<ACT>(a[3] * sv.w + tv.w);
        if constexpr (F8OUT) {
          uint wv = enc_pk<false>(v0, v1, 0u);
          wv = enc_pk<true>(v2, v3, wv);
          *(uint*)((uchar*)hout + (size_t)node * M + c0) = wv;
        } else {
          ushort4 o;
          o.x = f2bf(v0); o.y = f2bf(v1); o.z = f2bf(v2); o.w = f2bf(v3);
          *(ushort4*)((ushort*)hout + (size_t)node * M + c0) = o;
        }
      }
    }
  }
}

// ---------------- fused classifier: c1 + c2 + c3 + Wf-dot + sigmoid ----------
// block = 128 nodes, 512 threads (8 waves, 32 out-ch each). Dynamic LDS 144KB:
//   ldsW0[32KB] | ldsW1[32KB] | ldsH[64KB: 4 K-slabs x 128 nodes x 64ch] | ldsX[16KB]
__global__ __launch_bounds__(512) void cls_kernel(
    const ushort* __restrict__ xin,   // N x 128 bf16 (GIN output)
    const ushort* __restrict__ wc1,   // 256 x 128 bf16
    const float*  __restrict__ bc1,   // 256
    const ushort* __restrict__ wcl,   // 2 x 256 x 256 bf16
    const float*  __restrict__ bcl,   // 2 x 256
    const float*  __restrict__ wfv,   // 256
    const float*  __restrict__ bfp,   // 1
    float* __restrict__ out, int n)
{
  extern __shared__ char lds[];
  char* ldsW0 = lds;
  char* ldsW1 = lds + 32768;
  char* ldsH  = lds + 65536;
  char* ldsX  = lds + 131072;
  const int tid = threadIdx.x;
  const int wave = tid >> 6, lane = tid & 63;
  const int lr = lane & 15, lg = lane >> 4;
  const int n0 = blockIdx.x * 128;

  f32x4 acc[8][2];

  // stage a 256-row x 64-ch W slab (32KB); each of 8 waves covers 4KB
  auto stageW = [&](const ushort* wsrc, int K2, int s, char* dst) {
    #pragma unroll
    for (int i = 0; i < 4; ++i) {
      const int ub = wave * 4096 + i * 1024;
      const int a = ub + lane * 16;
      const int m = a >> 7;
      const int o = (a & 127) ^ ((m & 7) << 4);
      gload_lds16((const char*)wsrc + (size_t)m * K2 * 2 + s * 128 + o, dst + ub);
    }
  };
  // stage 128-node x 64-ch X slab (16KB); each wave covers 2KB
  auto stageX = [&](int s) {
    #pragma unroll
    for (int i = 0; i < 2; ++i) {
      const int ub = wave * 2048 + i * 1024;
      const int a = ub + lane * 16;
      const int m = a >> 7;
      const int o = (a & 127) ^ ((m & 7) << 4);
      int nd = n0 + m; if (nd >= n) nd = n - 1;
      gload_lds16((const char*)xin + (size_t)nd * 128 * 2 + s * 128 + o, ldsX + ub);
    }
  };
  // one K=64 slab of MFMAs: W rows wave*32+ct*16+lr, X rows rowOff+r*16+lr
  auto mfma_slab = [&](const char* wbuf, const char* xbase, int rowOff) {
    #pragma unroll
    for (int k0 = 0; k0 < 64; k0 += 32) {
      const int kb = (k0 + lg * 8) * 2;
      bf16x8 wfr[2];
      #pragma unroll
      for (int ct = 0; ct < 2; ++ct) {
        int m = wave * 32 + ct * 16 + lr;
        wfr[ct] = __builtin_bit_cast(bf16x8,
                  *(const uint4*)(wbuf + ((m * 128 + kb) ^ ((m & 7) << 4))));
      }
      #pragma unroll
      for (int r = 0; r < 8; ++r) {
        int xr = rowOff + r * 16 + lr;
        bf16x8 xf = __builtin_bit_cast(bf16x8,
                    *(const uint4*)(xbase + ((xr * 128 + kb) ^ ((xr & 7) << 4))));
        #pragma unroll
        for (int ct = 0; ct < 2; ++ct)
          acc[r][ct] = __builtin_amdgcn_mfma_f32_16x16x32_bf16(wfr[ct], xf, acc[r][ct], 0, 0, 0);
      }
    }
  };
  auto zacc = [&]() {
    #pragma unroll
    for (int r = 0; r < 8; ++r)
      #pragma unroll
      for (int c = 0; c < 2; ++c) acc[r][c] = (f32x4){0.f, 0.f, 0.f, 0.f};
  };
  // write this wave's 32ch x 128node tile into ldsH (K-slab layout)
  auto writeH = [&](const float* bias, bool act) {
    #pragma unroll
    for (int ct = 0; ct < 2; ++ct) {
      const int c0 = wave * 32 + ct * 16 + lg * 4;     // global channel 0..255
      const float4 bv = *(const float4*)(bias + c0);
      const int slab = c0 >> 6, cis = (c0 & 63) * 2;   // K-slab, byte col in slab
      #pragma unroll
      for (int r = 0; r < 8; ++r) {
        const int rowH = slab * 128 + r * 16 + lr;
        const f32x4 a = acc[r][ct];
        ushort4 o;
        if (act) {
          o.x = f2bf(actf<1>(a[0] + bv.x)); o.y = f2bf(actf<1>(a[1] + bv.y));
          o.z = f2bf(actf<1>(a[2] + bv.z)); o.w = f2bf(actf<1>(a[3] + bv.w));
        } else {
          o.x = f2bf(a[0] + bv.x); o.y = f2bf(a[1] + bv.y);
          o.z = f2bf(a[2] + bv.z); o.w = f2bf(a[3] + bv.w);
        }
        *(ushort4*)(ldsH + ((rowH * 128 + cis) ^ ((rowH & 7) << 4))) = o;
      }
    }
  };

  // ---- c1: h1 = X(128) @ Wc1^T + bc1 ----
  zacc();
  #pragma unroll
  for (int s = 0; s < 2; ++s) {
    if (s) __syncthreads();
    stageX(s);
    stageW(wc1, 128, s, ldsW0);
    asm volatile("s_waitcnt vmcnt(0)" ::: "memory");
    __syncthreads();
    mfma_slab(ldsW0, ldsX, 0);
  }
  __syncthreads();
  writeH(bc1, false);                               // h1 -> ldsH

  // ---- c2 (g=0): h2 = lrelu(h1 @ Wcl0^T + bcl0) -> ldsH
  // ---- c3 (g=1): logit = lrelu(h2 @ Wcl1^T + bcl1) . Wf + bf -> sigmoid
  for (int g = 0; g < 2; ++g) {
    const ushort* Wg = wcl + g * 65536;
    const float*  bg = bcl + g * 256;
    zacc();
    __syncthreads();                                // h-writes visible; ldsW free
    stageW(Wg, 256, 0, ldsW0);
    #pragma unroll
    for (int s = 0; s < 4; ++s) {
      char* cur = (s & 1) ? ldsW1 : ldsW0;
      char* nxt = (s & 1) ? ldsW0 : ldsW1;
      if (s + 1 < 4) {
        stageW(Wg, 256, s + 1, nxt);
        asm volatile("s_waitcnt vmcnt(4)" ::: "memory");
      } else {
        asm volatile("s_waitcnt vmcnt(0)" ::: "memory");
      }
      __syncthreads();
      mfma_slab(cur, ldsH, s * 128);
      __syncthreads();
    }
    if (g == 0) {
      writeH(bg, true);                             // h2 -> ldsH (in place)
    } else {
      float* red = (float*)ldsX;                    // 8 waves x 128 nodes
      #pragma unroll
      for (int r = 0; r < 8; ++r) {
        float p = 0.f;
        #pragma unroll
        for (int ct = 0; ct < 2; ++ct) {
          const int c0 = wave * 32 + ct * 16 + lg * 4;
          const float4 bv = *(const float4*)(bg + c0);
          const float4 wv = *(const float4*)(wfv + c0);
          const f32x4 a = acc[r][ct];
          p += actf<1>(a[0] + bv.x) * wv.x + actf<1>(a[1] + bv.y) * wv.y
             + actf<1>(a[2] + bv.z) * wv.z + actf<1>(a[3] + bv.w) * wv.w;
        }
        p += __shfl_xor(p, 16);
        p += __shfl_xor(p, 32);
        if (lg == 0) red[wave * 128 + r * 16 + lr] = p;
      }
      __syncthreads();
      if (tid < 128) {
        const int nd = n0 + tid;
        if (nd < n) {
          float logit = bfp[0];
          #pragma unroll
          for (int w = 0; w < 8; ++w) logit += red[w * 128 + tid];
          out[nd] = 1.f / (1.f + expf(-logit));
        }
      }
    }
  }
}

// ---------------- launch ----------------
extern "C" void kernel_launch(void* const* d_in, const int* in_sizes, int n_in,
                              void* d_out, int out_size, void* d_ws, size_t ws_size,
                              hipStream_t stream)
{
  const float* x    = (const float*)d_in[0];
  const int*   ei   = (const int*)d_in[1];
  const float* eps1 = (const float*)d_in[3];
  const float* W1   = (const float*)d_in[4];
  const float* b1   = (const float*)d_in[5];
  const float* g1   = (const float*)d_in[6];
  const float* be1  = (const float*)d_in[7];
  const float* m1   = (const float*)d_in[8];
  const float* v1   = (const float*)d_in[9];
  const float* epsL = (const float*)d_in[10];
  const float* WL   = (const float*)d_in[11];
  const float* bL   = (const float*)d_in[12];
  const float* gL   = (const float*)d_in[13];
  const float* beL  = (const float*)d_in[14];
  const float* mL   = (const float*)d_in[15];
  const float* vL   = (const float*)d_in[16];
  const float* Wc1  = (const float*)d_in[17];
  const float* bc1  = (const float*)d_in[18];
  const float* Wcl  = (const float*)d_in[19];
  const float* bcl  = (const float*)d_in[20];
  const float* Wf   = (const float*)d_in[21];
  const float* bfp  = (const float*)d_in[22];
  float* out = (float*)d_out;

  char* w = (char*)d_ws;
  size_t off = 0;
  auto alloc = [&](size_t bytes) {
    char* p = w + off;
    off += (bytes + 255) & ~(size_t)255;
    return p;
  };
  ushort* bufA   = (ushort*)alloc((size_t)NN * 256 * 2);   // 51.2 MB (bf16)
  ushort* bufB   = (ushort*)alloc((size_t)NN * 256 * 2);   // 51.2 MB (bf16 zin)
  uchar*  h8     = (uchar*)alloc((size_t)NN * 128);        // 12.8 MB fp8 table
  int*    rowp   = (int*)alloc((NN + 1) * 4);
  int*    deg    = (int*)alloc(NN * 4);
  int*    colb   = (int*)alloc((size_t)EE * 4);
  uint*   ebkt   = (uint*)alloc((size_t)EE * 4);
  int*    hist   = (int*)alloc((size_t)NCH * NBK * 4);     // 613 KB
  int*    bh     = (int*)alloc(NBK * 4);
  int*    boff   = (int*)alloc((NBK + 1) * 4);
  int*    partial= (int*)alloc(1024);
  ushort* wt1    = (ushort*)alloc(8192 * 2);
  ushort* wtL    = (ushort*)alloc(49152 * 2);
  ushort* wtc1   = (ushort*)alloc(32768 * 2);
  ushort* wtcl   = (ushort*)alloc(131072 * 2);
  float*  sc     = (float*)alloc(512 * 4);
  float*  tc     = (float*)alloc(512 * 4);
  (void)ws_size; (void)in_sizes; (void)n_in; (void)out_size;

  // multi-split CSR build (by dst), no global atomics in the scatter
  hipMemsetAsync(bh, 0, NBK * 4, stream);
  ms_hist_kernel<<<NCH, 256, 0, stream>>>(ei, hist, bh, EE);
  bkt_scan_kernel<<<1, 256, 0, stream>>>(bh, boff, EE);
  ms_offs_kernel<<<(NBK + 255) / 256, 256, 0, stream>>>(hist, boff);
  ms_scatter_kernel<<<NCH, 256, 0, stream>>>(ei, hist, ebkt, EE);
  bkt_deg_kernel<<<NBK, 256, 0, stream>>>(ebkt, boff, deg, NN);
  scan1_kernel<<<98, 256, 0, stream>>>(deg, rowp, partial, NN);
  scan2_kernel<<<1, 256, 0, stream>>>(partial, 98);
  scan3_kernel<<<(NN + 255) / 256, 256, 0, stream>>>(rowp, partial, NN, EE);
  bkt_fill_kernel<<<NBK, 256, 0, stream>>>(ebkt, boff, rowp, colb, NN);

  // prep
  bnprep_kernel<<<2, 256, 0, stream>>>(b1, g1, be1, m1, v1, bL, gL, beL, mL, vL, sc, tc);
  wtprep_kernel<<<864, 256, 0, stream>>>(W1, WL, Wc1, Wcl, wt1, wtL, wtc1, wtcl);
  xconv_kernel<<<(NN * CIN / 4 + 255) / 256, 256, 0, stream>>>(x, h8, NN * CIN / 4);

  const int GB = (NN + 127) / 128;   // 782 node-tiles

  // GIN layer 1 (64 -> 128), double lrelu; writes fp8 table
  agg_kernel<64><<<25000, 256, 0, stream>>>(h8, rowp, colb, eps1, bufB, NN);
  gemm_kernel<64, 128, 2, true, true><<<dim3(GB, 1), 256, 0, stream>>>(bufB, wt1, sc, tc, h8, NN);
  // GIN layers 2-3 (128 -> 128), double lrelu; write fp8 table
  for (int i = 0; i < 2; ++i) {
    agg_kernel<128><<<25000, 256, 0, stream>>>(h8, rowp, colb, epsL + i, bufB, NN);
    gemm_kernel<128, 128, 2, true, true><<<dim3(GB, 1), 256, 0, stream>>>(
        bufB, wtL + i * 16384, sc + 128 * (i + 1), tc + 128 * (i + 1), h8, NN);
  }
  // GIN layer 4: bf16 output for the fused classifier
  agg_kernel<128><<<25000, 256, 0, stream>>>(h8, rowp, colb, epsL + 2, bufB, NN);
  gemm_kernel<128, 128, 2, true, false><<<dim3(GB, 1), 256, 0, stream>>>(
      bufB, wtL + 2 * 16384, sc + 128 * 3, tc + 128 * 3, bufA, NN);
  // fused classifier + final (reads bufA, writes out)
  hipFuncSetAttribute(reinterpret_cast<const void*>(cls_kernel),
                      hipFuncAttributeMaxDynamicSharedMemorySize, 147456);
  cls_kernel<<<GB, 512, 147456, stream>>>(bufA, wtc1, bc1, wtcl, bcl, Wf, bfp, out, NN);
}